// Round 1
// baseline (9373.589 us; speedup 1.0000x reference)
//
#include <hip/hip_runtime.h>
#include <math.h>

#define NPIX 8000
#define IMH 80
#define IMW 100

// ---------------------------------------------------------------------------
// Generic 1x1 conv as GEMM: out[co][p] = sum_ci w[co][ci]*x[ci][p] + b[co] (+res)
// Grid: (ceil(8000/256), ceil(Co/16)). Block 256. 16 co per block.
// Weights staged transposed in LDS (stride 20 -> aligned float4 broadcast reads).
// ---------------------------------------------------------------------------
__global__ __launch_bounds__(256) void conv1x1_k(
    const float* __restrict__ x, const float* __restrict__ w,
    const float* __restrict__ b, const float* __restrict__ res,
    float* __restrict__ out, int Ci, int Co)
{
    __shared__ __align__(16) float wsT[256 * 20];
    const int tid = threadIdx.x;
    const int co0 = blockIdx.y * 16;

    const int nw = 16 * Ci;
    for (int e = tid; e < nw; e += 256) {
        int co = e / Ci;
        int ci = e - co * Ci;
        float v = 0.f;
        if (co0 + co < Co) v = w[(size_t)(co0 + co) * Ci + ci];
        wsT[ci * 20 + co] = v;
    }
    __syncthreads();

    const int p = blockIdx.x * 256 + tid;
    if (p >= NPIX) return;

    float acc[16];
#pragma unroll
    for (int k = 0; k < 16; k++) acc[k] = 0.f;

#pragma unroll 4
    for (int ci = 0; ci < Ci; ci++) {
        float xv = x[(size_t)ci * NPIX + p];
        const float4 w0 = *(const float4*)&wsT[ci * 20 + 0];
        const float4 w1 = *(const float4*)&wsT[ci * 20 + 4];
        const float4 w2 = *(const float4*)&wsT[ci * 20 + 8];
        const float4 w3 = *(const float4*)&wsT[ci * 20 + 12];
        acc[0]  += w0.x * xv; acc[1]  += w0.y * xv; acc[2]  += w0.z * xv; acc[3]  += w0.w * xv;
        acc[4]  += w1.x * xv; acc[5]  += w1.y * xv; acc[6]  += w1.z * xv; acc[7]  += w1.w * xv;
        acc[8]  += w2.x * xv; acc[9]  += w2.y * xv; acc[10] += w2.z * xv; acc[11] += w2.w * xv;
        acc[12] += w3.x * xv; acc[13] += w3.y * xv; acc[14] += w3.z * xv; acc[15] += w3.w * xv;
    }

#pragma unroll
    for (int k = 0; k < 16; k++) {
        int co = co0 + k;
        if (co < Co) {
            float v = acc[k] + b[co];
            size_t idx = (size_t)co * NPIX + p;
            if (res) v += res[idx];
            out[idx] = v;
        }
    }
}

// ---------------------------------------------------------------------------
// Flash attention, fp32. Q=theta raw-(8000x128), K^T=phi (128x8000), V=g raw.
// Block: 256 threads, 32 Q-rows; 125 tiles of 64 q. Online softmax (m,l).
// blockIdx.y selects the tl / br problem.
// ---------------------------------------------------------------------------
__global__ __launch_bounds__(256) void flash_k(
    const float* __restrict__ th0, const float* __restrict__ ph0,
    const float* __restrict__ g0, float* __restrict__ y0,
    const float* __restrict__ th1, const float* __restrict__ ph1,
    const float* __restrict__ g1, float* __restrict__ y1)
{
    const int wb = blockIdx.y;
    const float* TH = wb ? th1 : th0;
    const float* PH = wb ? ph1 : ph0;
    const float* G  = wb ? g1  : g0;
    float*       Y  = wb ? y1  : y0;

    const int r0  = blockIdx.x * 32;
    const int tid = threadIdx.x;

    __shared__ __align__(16) float thT[128 * 36];  // theta transposed [c][r]
    __shared__ __align__(16) float phs[128 * 65];  // phi tile [c][q]; reused as g tile [q][c]
    __shared__ __align__(16) float ss[32 * 68];    // scores / probs [r][q]
    __shared__ __align__(16) float ys[32 * 128];   // output accumulator
    __shared__ float ms[32], ls[32], scl[32];

    // load theta rows (coalesced) -> transposed LDS (one-time)
#pragma unroll
    for (int k = 0; k < 16; k++) {
        int e = k * 256 + tid;
        int r = e >> 7, c = e & 127;
        thT[c * 36 + r] = TH[(size_t)(r0 + r) * 128 + c];
    }
#pragma unroll
    for (int k = 0; k < 16; k++) ys[k * 256 + tid] = 0.f;
    if (tid < 32) { ms[tid] = -INFINITY; ls[tid] = 0.f; }
    __syncthreads();

    const int qi = tid & 63;        // QK mapping
    const int rg = tid >> 6;        // wave id -> 8-row group (wave-uniform)
    const int sr = tid >> 3;        // softmax row
    const int si = tid & 7;
    const int cc = tid & 127;       // PV mapping
    const int rr = tid >> 7;

    for (int t = 0; t < 125; ++t) {
        const int q0 = t * 64;

        // stage phi tile [c][q]
#pragma unroll
        for (int k = 0; k < 32; k++) {
            int e = k * 256 + tid;
            int c = e >> 6, q = e & 63;
            phs[c * 65 + q] = PH[(size_t)c * NPIX + q0 + q];
        }
        __syncthreads();

        // S tile: each thread one q column x 8 rows
        float a[8];
#pragma unroll
        for (int j = 0; j < 8; j++) a[j] = 0.f;
#pragma unroll 4
        for (int c = 0; c < 128; c++) {
            float pv = phs[c * 65 + qi];
            const float4 t0 = *(const float4*)&thT[c * 36 + rg * 8];
            const float4 t1 = *(const float4*)&thT[c * 36 + rg * 8 + 4];
            a[0] += t0.x * pv; a[1] += t0.y * pv; a[2] += t0.z * pv; a[3] += t0.w * pv;
            a[4] += t1.x * pv; a[5] += t1.y * pv; a[6] += t1.z * pv; a[7] += t1.w * pv;
        }
#pragma unroll
        for (int j = 0; j < 8; j++) ss[(rg * 8 + j) * 68 + qi] = a[j];
        __syncthreads();

        // online softmax for the tile (8 lanes per row)
        {
            int base = sr * 68 + si * 8;
            float mx = -INFINITY;
#pragma unroll
            for (int j = 0; j < 8; j++) mx = fmaxf(mx, ss[base + j]);
            mx = fmaxf(mx, __shfl_xor(mx, 1));
            mx = fmaxf(mx, __shfl_xor(mx, 2));
            mx = fmaxf(mx, __shfl_xor(mx, 4));
            float mold = ms[sr];
            float mnew = fmaxf(mold, mx);
            float sum = 0.f;
#pragma unroll
            for (int j = 0; j < 8; j++) {
                float pe = __expf(ss[base + j] - mnew);
                ss[base + j] = pe;
                sum += pe;
            }
            sum += __shfl_xor(sum, 1);
            sum += __shfl_xor(sum, 2);
            sum += __shfl_xor(sum, 4);
            if (si == 0) {
                float sc = __expf(mold - mnew);
                scl[sr] = sc;
                ls[sr]  = ls[sr] * sc + sum;
                ms[sr]  = mnew;
            }
        }

        // stage g tile [q][c] into phs (phi reads all completed before last barrier)
#pragma unroll
        for (int k = 0; k < 32; k++) {
            int e = k * 256 + tid;
            int q = e >> 7, c = e & 127;
            phs[q * 128 + c] = G[(size_t)(q0 + q) * 128 + c];
        }
        __syncthreads();

        // PV: thread owns column cc, 16 rows (rr, rr+2, ...). g reused across rows.
        {
            float accv[16];
#pragma unroll
            for (int k = 0; k < 16; k++) {
                int r = rr + 2 * k;
                accv[k] = ys[r * 128 + cc] * scl[r];
            }
            for (int qb = 0; qb < 16; qb++) {
                float g0v = phs[(qb * 4 + 0) * 128 + cc];
                float g1v = phs[(qb * 4 + 1) * 128 + cc];
                float g2v = phs[(qb * 4 + 2) * 128 + cc];
                float g3v = phs[(qb * 4 + 3) * 128 + cc];
#pragma unroll
                for (int k = 0; k < 16; k++) {
                    int r = rr + 2 * k;
                    const float4 s4 = *(const float4*)&ss[r * 68 + qb * 4];
                    accv[k] += s4.x * g0v + s4.y * g1v + s4.z * g2v + s4.w * g3v;
                }
            }
#pragma unroll
            for (int k = 0; k < 16; k++) ys[(rr + 2 * k) * 128 + cc] = accv[k];
        }
        __syncthreads();
    }

    // epilogue: divide by l, write Y (row-major 8000x128 flat)
#pragma unroll
    for (int k = 0; k < 16; k++) {
        int e = k * 256 + tid;
        int r = e >> 7, c = e & 127;
        Y[(size_t)(r0 + r) * 128 + c] = ys[r * 128 + c] / ls[r];
    }
}

// ---------------------------------------------------------------------------
// conv3x3 (SAME, cross-correlation) + bias + ReLU for a tl/br head pair.
// Block: 256 threads; spatial tile 10x50 (2 stacked pixels/thread), 16 co.
// Grid: (16 spatial, 16 co-tiles, 2 heads).
// ---------------------------------------------------------------------------
__global__ __launch_bounds__(256) void conv3x3_pair_k(
    const float* __restrict__ in0, const float* __restrict__ in1,
    const float* __restrict__ w0p, const float* __restrict__ b0p,
    const float* __restrict__ w1p, const float* __restrict__ b1p,
    float* __restrict__ out0, float* __restrict__ out1)
{
    const int head = blockIdx.z;
    const float* in = head ? in1 : in0;
    const float* wp = head ? w1p : w0p;
    const float* bp = head ? b1p : b0p;
    float* out      = head ? out1 : out0;

    const int tid = threadIdx.x;
    const int co0 = blockIdx.y * 16;
    const int sy  = (blockIdx.x >> 1) * 10;
    const int sx  = (blockIdx.x & 1) * 50;

    __shared__ __align__(16) float xs[8 * 12 * 52];   // [ci][row -1..10][col -1..50]
    __shared__ __align__(16) float wls[16 * 8 * 12];  // [co][ci][tap(9, pad 12)]

    float acc[16][2];
#pragma unroll
    for (int a = 0; a < 16; a++) { acc[a][0] = 0.f; acc[a][1] = 0.f; }

    const int ty = tid / 50;
    const int tx = tid - ty * 50;

    for (int ci0 = 0; ci0 < 256; ci0 += 8) {
        __syncthreads();
        // stage input tile with halo (zero padded)
        for (int e = tid; e < 8 * 12 * 52; e += 256) {
            int ci = e / 624;
            int r2 = e - ci * 624;
            int rw = r2 / 52;
            int cl = r2 - rw * 52;
            int gy = sy - 1 + rw, gx = sx - 1 + cl;
            float v = 0.f;
            if (gy >= 0 && gy < IMH && gx >= 0 && gx < IMW)
                v = in[(size_t)(ci0 + ci) * NPIX + gy * IMW + gx];
            xs[e] = v;
        }
        // stage weights
        for (int e = tid; e < 1152; e += 256) {
            int co = e / 72;
            int r2 = e - co * 72;
            int ci = r2 / 9;
            int tap = r2 - ci * 9;
            wls[co * 96 + ci * 12 + tap] =
                wp[(size_t)(co0 + co) * 2304 + (ci0 + ci) * 9 + tap];
        }
        __syncthreads();

        if (tid < 250) {
#pragma unroll
            for (int ci = 0; ci < 8; ci++) {
                float xv[4][3];
#pragma unroll
                for (int j = 0; j < 4; j++)
#pragma unroll
                    for (int k2 = 0; k2 < 3; k2++)
                        xv[j][k2] = xs[ci * 624 + (2 * ty + j) * 52 + tx + k2];
#pragma unroll
                for (int co = 0; co < 16; co++) {
                    const float4 wa = *(const float4*)&wls[co * 96 + ci * 12 + 0];
                    const float4 wb = *(const float4*)&wls[co * 96 + ci * 12 + 4];
                    const float  wc = wls[co * 96 + ci * 12 + 8];
                    acc[co][0] += wa.x * xv[0][0] + wa.y * xv[0][1] + wa.z * xv[0][2]
                                + wa.w * xv[1][0] + wb.x * xv[1][1] + wb.y * xv[1][2]
                                + wb.z * xv[2][0] + wb.w * xv[2][1] + wc * xv[2][2];
                    acc[co][1] += wa.x * xv[1][0] + wa.y * xv[1][1] + wa.z * xv[1][2]
                                + wa.w * xv[2][0] + wb.x * xv[2][1] + wb.y * xv[2][2]
                                + wb.z * xv[3][0] + wb.w * xv[3][1] + wc * xv[3][2];
                }
            }
        }
    }

    if (tid < 250) {
#pragma unroll
        for (int co = 0; co < 16; co++) {
            float bb = bp[co0 + co];
#pragma unroll
            for (int j = 0; j < 2; j++) {
                int oy = sy + 2 * ty + j;
                float v = acc[co][j] + bb;
                out[(size_t)(co0 + co) * NPIX + oy * IMW + sx + tx] = fmaxf(v, 0.f);
            }
        }
    }
}

// ---------------------------------------------------------------------------
extern "C" void kernel_launch(void* const* d_in, const int* in_sizes, int n_in,
                              void* d_out, int out_size, void* d_ws, size_t ws_size,
                              hipStream_t stream)
{
    const float* feat = (const float*)d_in[0];
    auto F = [&](int i) { return (const float*)d_in[i]; };

    float* out = (float*)d_out;
    float* wsf = (float*)d_ws;

    const size_t M = 1024000;  // 128*8000 floats
    const bool big = ws_size >= (size_t)12 * M * sizeof(float);

    // head table: {w1,b1,w2,b2, out offset, Co}
    struct HD { int w1, b1, w2, b2; size_t off; int co; };
    const HD pairs[3][2] = {
        { {17,18,19,20, 0u,       80}, {21,22,23,24, 640000u,  80} },
        { {25,26,27,28, 1280000u,  1}, {29,30,31,32, 1288000u,  1} },
        { {33,34,35,36, 1296000u,  2}, {37,38,39,40, 1312000u,  2} },
    };

    float *nl_tl, *nl_br, *rb0, *rb1;

    if (big) {
        float* th_tl = wsf + 0 * M;  float* ph_tl = wsf + 1 * M;  float* g_tl = wsf + 2 * M;
        float* th_br = wsf + 3 * M;  float* ph_br = wsf + 4 * M;  float* g_br = wsf + 5 * M;
        float* y_tl  = wsf + 6 * M;  float* y_br  = wsf + 7 * M;
        nl_tl = wsf + 8 * M;   // 2M floats
        nl_br = wsf + 10 * M;  // 2M floats
        rb0 = wsf + 0;         // reuse attn scratch after attention is done
        rb1 = wsf + 2 * M;

        dim3 gtpg(32, 8);
        conv1x1_k<<<gtpg, 256, 0, stream>>>(feat, F(1),  F(2),  nullptr, th_tl, 256, 128);
        conv1x1_k<<<gtpg, 256, 0, stream>>>(feat, F(3),  F(4),  nullptr, ph_tl, 256, 128);
        conv1x1_k<<<gtpg, 256, 0, stream>>>(feat, F(5),  F(6),  nullptr, g_tl,  256, 128);
        conv1x1_k<<<gtpg, 256, 0, stream>>>(feat, F(9),  F(10), nullptr, th_br, 256, 128);
        conv1x1_k<<<gtpg, 256, 0, stream>>>(feat, F(11), F(12), nullptr, ph_br, 256, 128);
        conv1x1_k<<<gtpg, 256, 0, stream>>>(feat, F(13), F(14), nullptr, g_br,  256, 128);

        flash_k<<<dim3(250, 2), 256, 0, stream>>>(th_tl, ph_tl, g_tl, y_tl,
                                                  th_br, ph_br, g_br, y_br);

        conv1x1_k<<<dim3(32, 16), 256, 0, stream>>>(y_tl, F(7),  F(8),  feat, nl_tl, 128, 256);
        conv1x1_k<<<dim3(32, 16), 256, 0, stream>>>(y_br, F(15), F(16), feat, nl_br, 128, 256);
    } else {
        // small-workspace fallback: serialize tl/br attention
        float* th = wsf + 0 * M;  float* ph = wsf + 1 * M;
        float* g  = wsf + 2 * M;  float* y  = wsf + 3 * M;
        nl_tl = wsf + 4 * M;
        nl_br = wsf + 6 * M;
        rb0 = wsf + 0;
        rb1 = wsf + 2 * M;

        dim3 gtpg(32, 8);
        conv1x1_k<<<gtpg, 256, 0, stream>>>(feat, F(1),  F(2),  nullptr, th, 256, 128);
        conv1x1_k<<<gtpg, 256, 0, stream>>>(feat, F(3),  F(4),  nullptr, ph, 256, 128);
        conv1x1_k<<<gtpg, 256, 0, stream>>>(feat, F(5),  F(6),  nullptr, g,  256, 128);
        flash_k<<<dim3(250, 1), 256, 0, stream>>>(th, ph, g, y, th, ph, g, y);
        conv1x1_k<<<dim3(32, 16), 256, 0, stream>>>(y, F(7), F(8), feat, nl_tl, 128, 256);

        conv1x1_k<<<gtpg, 256, 0, stream>>>(feat, F(9),  F(10), nullptr, th, 256, 128);
        conv1x1_k<<<gtpg, 256, 0, stream>>>(feat, F(11), F(12), nullptr, ph, 256, 128);
        conv1x1_k<<<gtpg, 256, 0, stream>>>(feat, F(13), F(14), nullptr, g,  256, 128);
        flash_k<<<dim3(250, 1), 256, 0, stream>>>(th, ph, g, y, th, ph, g, y);
        conv1x1_k<<<dim3(32, 16), 256, 0, stream>>>(y, F(15), F(16), feat, nl_br, 128, 256);
    }

    // heads: conv3x3+relu pair, then 1x1 per head
    for (int pi = 0; pi < 3; pi++) {
        const HD& A = pairs[pi][0];
        const HD& Bx = pairs[pi][1];
        conv3x3_pair_k<<<dim3(16, 16, 2), 256, 0, stream>>>(
            nl_tl, nl_br, F(A.w1), F(A.b1), F(Bx.w1), F(Bx.b1), rb0, rb1);
        int gy = (A.co + 15) / 16;
        conv1x1_k<<<dim3(32, gy), 256, 0, stream>>>(rb0, F(A.w2), F(A.b2), nullptr,
                                                    out + A.off, 256, A.co);
        conv1x1_k<<<dim3(32, gy), 256, 0, stream>>>(rb1, F(Bx.w2), F(Bx.b2), nullptr,
                                                    out + Bx.off, 256, Bx.co);
    }
}

// Round 3
// 3738.464 us; speedup vs baseline: 2.5073x; 2.5073x over previous
//
#include <hip/hip_runtime.h>
#include <hip/hip_bf16.h>
#include <math.h>
#include <type_traits>

#define NPIX 8000
#define IMH 80
#define IMW 100

typedef __attribute__((ext_vector_type(8))) short short8v;
typedef __attribute__((ext_vector_type(4))) short short4v;
typedef __attribute__((ext_vector_type(4))) float f32x4;

__device__ inline short f2bf(float f) {
    __hip_bfloat16 h = __float2bfloat16(f);
    return *reinterpret_cast<short*>(&h);
}
__device__ inline float bf2f(short s) {
    __hip_bfloat16 h;
    *reinterpret_cast<short*>(&h) = s;
    return __bfloat162float(h);
}

// ---------------------------------------------------------------------------
// 1x1 conv as GEMM, templated on in/out dtype and transposed store.
// x channel-major [Ci][8000]. TRANS=false: out[co][p]; TRANS=true: out[p][co].
// ---------------------------------------------------------------------------
template <class TI, class TO, bool TRANS>
__global__ __launch_bounds__(256) void conv1x1_t(
    const TI* __restrict__ x, const float* __restrict__ w,
    const float* __restrict__ b, const float* __restrict__ res,
    TO* __restrict__ out, int Ci, int Co)
{
    __shared__ __align__(16) float wsT[256 * 20];
    const int tid = threadIdx.x;
    const int co0 = blockIdx.y * 16;

    const int nw = 16 * Ci;
    for (int e = tid; e < nw; e += 256) {
        int co = e / Ci;
        int ci = e - co * Ci;
        float v = 0.f;
        if (co0 + co < Co) v = w[(size_t)(co0 + co) * Ci + ci];
        wsT[ci * 20 + co] = v;
    }
    __syncthreads();

    const int p = blockIdx.x * 256 + tid;
    if (p >= NPIX) return;

    float acc[16];
#pragma unroll
    for (int k = 0; k < 16; k++) acc[k] = 0.f;

#pragma unroll 4
    for (int ci = 0; ci < Ci; ci++) {
        float xv;
        if constexpr (std::is_same_v<TI, short>) {
            short t = x[(size_t)ci * NPIX + p];
            xv = bf2f(t);
        } else {
            xv = x[(size_t)ci * NPIX + p];
        }
        const float4 w0 = *(const float4*)&wsT[ci * 20 + 0];
        const float4 w1 = *(const float4*)&wsT[ci * 20 + 4];
        const float4 w2 = *(const float4*)&wsT[ci * 20 + 8];
        const float4 w3 = *(const float4*)&wsT[ci * 20 + 12];
        acc[0]  += w0.x * xv; acc[1]  += w0.y * xv; acc[2]  += w0.z * xv; acc[3]  += w0.w * xv;
        acc[4]  += w1.x * xv; acc[5]  += w1.y * xv; acc[6]  += w1.z * xv; acc[7]  += w1.w * xv;
        acc[8]  += w2.x * xv; acc[9]  += w2.y * xv; acc[10] += w2.z * xv; acc[11] += w2.w * xv;
        acc[12] += w3.x * xv; acc[13] += w3.y * xv; acc[14] += w3.z * xv; acc[15] += w3.w * xv;
    }

#pragma unroll
    for (int k = 0; k < 16; k++) {
        int co = co0 + k;
        if (co < Co) {
            float v = acc[k] + b[co];
            if constexpr (TRANS) {
                out[(size_t)p * Co + co] = (TO)f2bf(v);
            } else {
                size_t idx = (size_t)co * NPIX + p;
                if (res) v += res[idx];
                if constexpr (std::is_same_v<TO, short>)
                    out[idx] = f2bf(v);
                else
                    out[idx] = v;
            }
        }
    }
}

// ---------------------------------------------------------------------------
// Transpose raw (8000x128) bf16 view -> [128][8000] bf16. Grid (125,2,2).
// ---------------------------------------------------------------------------
__global__ __launch_bounds__(256) void transp_k(
    const short* __restrict__ g0, short* __restrict__ o0,
    const short* __restrict__ g1, short* __restrict__ o1)
{
    const short* G = blockIdx.z ? g1 : g0;
    short* O = blockIdx.z ? o1 : o0;
    __shared__ __align__(16) short ts[64][68];
    const int tid = threadIdx.x;
    const int q0 = blockIdx.x * 64, d0 = blockIdx.y * 64;

#pragma unroll
    for (int k = 0; k < 4; k++) {
        int f = k * 256 + tid;
        int q = f >> 4, d4 = f & 15;
        *(short4v*)&ts[q][d4 * 4] =
            *(const short4v*)(G + (size_t)(q0 + q) * 128 + d0 + d4 * 4);
    }
    __syncthreads();
#pragma unroll
    for (int k = 0; k < 4; k++) {
        int f = k * 256 + tid;
        int d = f >> 4, q4 = f & 15;
        short4v v;
        v[0] = ts[q4 * 4 + 0][d];
        v[1] = ts[q4 * 4 + 1][d];
        v[2] = ts[q4 * 4 + 2][d];
        v[3] = ts[q4 * 4 + 3][d];
        *(short4v*)(O + (size_t)(d0 + d) * NPIX + q0 + q4 * 4) = v;
    }
}

// ---------------------------------------------------------------------------
// Flash attention with bf16 MFMA. Q-tile 64 rows (wave w owns rows 16w..16w+15),
// KV-tile 64, 125 iterations, no softmax scale (faithful to reference).
// thb: raw flat bf16 (Q rows contiguous). phT: [q][c] bf16. gT: [d][q] bf16.
// Y: raw flat bf16 (8000x128). Grid (125, 2 problems), 256 threads.
// ---------------------------------------------------------------------------
__global__ __launch_bounds__(256) void flash_mfma_k(
    const short* __restrict__ th0, const short* __restrict__ pT0,
    const short* __restrict__ gT0, short* __restrict__ y0,
    const short* __restrict__ th1, const short* __restrict__ pT1,
    const short* __restrict__ gT1, short* __restrict__ y1)
{
    const int pb = blockIdx.y;
    const short* TH = pb ? th1 : th0;
    const short* PT = pb ? pT1 : pT0;
    const short* GT = pb ? gT1 : gT0;
    short*       Y  = pb ? y1  : y0;

    __shared__ __align__(16) short kls[64 * 136];  // K^T tile [q][c], pad 8
    __shared__ __align__(16) short vls[128 * 72];  // V^T tile [d][q], pad 8
    __shared__ __align__(16) short pls[64 * 72];   // P tile [r][q], pad 8

    const int tid = threadIdx.x;
    const int w = tid >> 6, l = tid & 63, lg = l >> 4, li = l & 15;
    const int r0 = blockIdx.x * 64;
    const int wr = r0 + w * 16;

    // Q fragments: A[row=li][k = ks*32 + lg*8 + i], rows are raw flat slices.
    short8v qf[4];
#pragma unroll
    for (int ks = 0; ks < 4; ks++)
        qf[ks] = *(const short8v*)(TH + (size_t)(wr + li) * 128 + ks * 32 + lg * 8);

    f32x4 acc_o[8] = {};
    float mj[4] = {-1e30f, -1e30f, -1e30f, -1e30f};
    float lj[4] = {0.f, 0.f, 0.f, 0.f};

    for (int t = 0; t < 125; ++t) {
        const int q0 = t * 64;

        // stage K^T tile: contiguous rows of phT
#pragma unroll
        for (int k = 0; k < 4; k++) {
            int f = k * 256 + tid;
            int q = f >> 4, c8 = f & 15;
            *(short8v*)(kls + q * 136 + c8 * 8) =
                *(const short8v*)(PT + (size_t)(q0 + q) * 128 + c8 * 8);
        }
        // stage V^T tile: rows of gT
#pragma unroll
        for (int k = 0; k < 4; k++) {
            int f = k * 256 + tid;
            int d = f >> 3, q8 = f & 7;
            *(short8v*)(vls + d * 72 + q8 * 8) =
                *(const short8v*)(GT + (size_t)d * NPIX + q0 + q8 * 8);
        }
        __syncthreads();

        // QK^T: S[r][kv], 4 col-subtiles x 4 k-steps
        f32x4 accs[4] = {};
#pragma unroll
        for (int ks = 0; ks < 4; ks++) {
#pragma unroll
            for (int n = 0; n < 4; n++) {
                short8v bb = *(const short8v*)(kls + (n * 16 + li) * 136 + ks * 32 + lg * 8);
                accs[n] = __builtin_amdgcn_mfma_f32_16x16x32_bf16(qf[ks], bb, accs[n], 0, 0, 0);
            }
        }

        // online softmax; lane owns rows lg*4+j of the wave's 16
#pragma unroll
        for (int j = 0; j < 4; j++) {
            float sm = fmaxf(fmaxf(accs[0][j], accs[1][j]), fmaxf(accs[2][j], accs[3][j]));
            sm = fmaxf(sm, __shfl_xor(sm, 1));
            sm = fmaxf(sm, __shfl_xor(sm, 2));
            sm = fmaxf(sm, __shfl_xor(sm, 4));
            sm = fmaxf(sm, __shfl_xor(sm, 8));
            float mo = mj[j];
            float mn = fmaxf(mo, sm);
            float sc = __expf(mo - mn);
            mj[j] = mn;
            float ps = 0.f;
            int row = w * 16 + lg * 4 + j;
#pragma unroll
            for (int n = 0; n < 4; n++) {
                float pe = __expf(accs[n][j] - mn);
                ps += pe;
                pls[row * 72 + n * 16 + li] = f2bf(pe);
            }
            ps += __shfl_xor(ps, 1);
            ps += __shfl_xor(ps, 2);
            ps += __shfl_xor(ps, 4);
            ps += __shfl_xor(ps, 8);
            lj[j] = lj[j] * sc + ps;
#pragma unroll
            for (int d = 0; d < 8; d++) acc_o[d][j] *= sc;
        }

        // PV: A = P (wave-local rows, same-wave LDS dependency), B = V^T tile
        __syncthreads();
#pragma unroll
        for (int ks = 0; ks < 2; ks++) {
            short8v aa = *(const short8v*)(pls + (w * 16 + li) * 72 + ks * 32 + lg * 8);
#pragma unroll
            for (int d = 0; d < 8; d++) {
                short8v bb = *(const short8v*)(vls + (d * 16 + li) * 72 + ks * 32 + lg * 8);
                acc_o[d] = __builtin_amdgcn_mfma_f32_16x16x32_bf16(aa, bb, acc_o[d], 0, 0, 0);
            }
        }
        __syncthreads();
    }

    // epilogue: normalize and store raw flat bf16
#pragma unroll
    for (int d = 0; d < 8; d++) {
#pragma unroll
        for (int j = 0; j < 4; j++) {
            int row = r0 + w * 16 + lg * 4 + j;
            float v = acc_o[d][j] / lj[j];
            Y[(size_t)row * 128 + d * 16 + li] = f2bf(v);
        }
    }
}

// ---------------------------------------------------------------------------
// conv3x3 (SAME) + bias + ReLU pair (unchanged from round 1).
// ---------------------------------------------------------------------------
__global__ __launch_bounds__(256) void conv3x3_pair_k(
    const float* __restrict__ in0, const float* __restrict__ in1,
    const float* __restrict__ w0p, const float* __restrict__ b0p,
    const float* __restrict__ w1p, const float* __restrict__ b1p,
    float* __restrict__ out0, float* __restrict__ out1)
{
    const int head = blockIdx.z;
    const float* in = head ? in1 : in0;
    const float* wp = head ? w1p : w0p;
    const float* bp = head ? b1p : b0p;
    float* out      = head ? out1 : out0;

    const int tid = threadIdx.x;
    const int co0 = blockIdx.y * 16;
    const int sy  = (blockIdx.x >> 1) * 10;
    const int sx  = (blockIdx.x & 1) * 50;

    __shared__ __align__(16) float xs[8 * 12 * 52];
    __shared__ __align__(16) float wls[16 * 8 * 12];

    float acc[16][2];
#pragma unroll
    for (int a = 0; a < 16; a++) { acc[a][0] = 0.f; acc[a][1] = 0.f; }

    const int ty = tid / 50;
    const int tx = tid - ty * 50;

    for (int ci0 = 0; ci0 < 256; ci0 += 8) {
        __syncthreads();
        for (int e = tid; e < 8 * 12 * 52; e += 256) {
            int ci = e / 624;
            int r2 = e - ci * 624;
            int rw = r2 / 52;
            int cl = r2 - rw * 52;
            int gy = sy - 1 + rw, gx = sx - 1 + cl;
            float v = 0.f;
            if (gy >= 0 && gy < IMH && gx >= 0 && gx < IMW)
                v = in[(size_t)(ci0 + ci) * NPIX + gy * IMW + gx];
            xs[e] = v;
        }
        for (int e = tid; e < 1152; e += 256) {
            int co = e / 72;
            int r2 = e - co * 72;
            int ci = r2 / 9;
            int tap = r2 - ci * 9;
            wls[co * 96 + ci * 12 + tap] =
                wp[(size_t)(co0 + co) * 2304 + (ci0 + ci) * 9 + tap];
        }
        __syncthreads();

        if (tid < 250) {
#pragma unroll
            for (int ci = 0; ci < 8; ci++) {
                float xv[4][3];
#pragma unroll
                for (int j = 0; j < 4; j++)
#pragma unroll
                    for (int k2 = 0; k2 < 3; k2++)
                        xv[j][k2] = xs[ci * 624 + (2 * ty + j) * 52 + tx + k2];
#pragma unroll
                for (int co = 0; co < 16; co++) {
                    const float4 wa = *(const float4*)&wls[co * 96 + ci * 12 + 0];
                    const float4 wb = *(const float4*)&wls[co * 96 + ci * 12 + 4];
                    const float  wc = wls[co * 96 + ci * 12 + 8];
                    acc[co][0] += wa.x * xv[0][0] + wa.y * xv[0][1] + wa.z * xv[0][2]
                                + wa.w * xv[1][0] + wb.x * xv[1][1] + wb.y * xv[1][2]
                                + wb.z * xv[2][0] + wb.w * xv[2][1] + wc * xv[2][2];
                    acc[co][1] += wa.x * xv[1][0] + wa.y * xv[1][1] + wa.z * xv[1][2]
                                + wa.w * xv[2][0] + wb.x * xv[2][1] + wb.y * xv[2][2]
                                + wb.z * xv[3][0] + wb.w * xv[3][1] + wc * xv[3][2];
                }
            }
        }
    }

    if (tid < 250) {
#pragma unroll
        for (int co = 0; co < 16; co++) {
            float bb = bp[co0 + co];
#pragma unroll
            for (int j = 0; j < 2; j++) {
                int oy = sy + 2 * ty + j;
                float v = acc[co][j] + bb;
                out[(size_t)(co0 + co) * NPIX + oy * IMW + sx + tx] = fmaxf(v, 0.f);
            }
        }
    }
}

// ---------------------------------------------------------------------------
extern "C" void kernel_launch(void* const* d_in, const int* in_sizes, int n_in,
                              void* d_out, int out_size, void* d_ws, size_t ws_size,
                              hipStream_t stream)
{
    const float* feat = (const float*)d_in[0];
    auto F = [&](int i) { return (const float*)d_in[i]; };

    float* out = (float*)d_out;
    char* base = (char*)d_ws;

    const size_t MB = 1u << 20;
    // per-problem bf16 block (8 MB): thb, phT, gb, gT (2 MB each)
    short* thb[2] = { (short*)(base + 0 * MB),  (short*)(base + 8 * MB)  };
    short* phT[2] = { (short*)(base + 2 * MB),  (short*)(base + 10 * MB) };
    short* gb[2]  = { (short*)(base + 4 * MB),  (short*)(base + 12 * MB) };
    short* gT[2]  = { (short*)(base + 6 * MB),  (short*)(base + 14 * MB) };
    short* yb[2]  = { (short*)(base + 16 * MB), (short*)(base + 18 * MB) };
    // nl overwrites the (dead) bf16 QKV region; rb overwrites yb after W-conv
    float* nl[2]  = { (float*)(base + 0 * MB),  (float*)(base + 8 * MB)  };
    float* rb0    = (float*)(base + 16 * MB);
    float* rb1    = (float*)(base + 24 * MB);

    // producers: theta (raw bf16), phi (transposed bf16), g (raw bf16), x2 problems
    dim3 gq(32, 8);
    conv1x1_t<float, short, false><<<gq, 256, 0, stream>>>(feat, F(1),  F(2),  nullptr, thb[0], 256, 128);
    conv1x1_t<float, short, true ><<<gq, 256, 0, stream>>>(feat, F(3),  F(4),  nullptr, phT[0], 256, 128);
    conv1x1_t<float, short, false><<<gq, 256, 0, stream>>>(feat, F(5),  F(6),  nullptr, gb[0],  256, 128);
    conv1x1_t<float, short, false><<<gq, 256, 0, stream>>>(feat, F(9),  F(10), nullptr, thb[1], 256, 128);
    conv1x1_t<float, short, true ><<<gq, 256, 0, stream>>>(feat, F(11), F(12), nullptr, phT[1], 256, 128);
    conv1x1_t<float, short, false><<<gq, 256, 0, stream>>>(feat, F(13), F(14), nullptr, gb[1],  256, 128);

    transp_k<<<dim3(125, 2, 2), 256, 0, stream>>>(gb[0], gT[0], gb[1], gT[1]);

    flash_mfma_k<<<dim3(125, 2), 256, 0, stream>>>(thb[0], phT[0], gT[0], yb[0],
                                                   thb[1], phT[1], gT[1], yb[1]);

    // W-conv + residual (bf16 in, fp32 out)
    conv1x1_t<short, float, false><<<dim3(32, 16), 256, 0, stream>>>(yb[0], F(7),  F(8),  feat, nl[0], 128, 256);
    conv1x1_t<short, float, false><<<dim3(32, 16), 256, 0, stream>>>(yb[1], F(15), F(16), feat, nl[1], 128, 256);

    // heads
    struct HD { int w1, b1, w2, b2; size_t off; int co; };
    const HD pairs[3][2] = {
        { {17,18,19,20, 0u,       80}, {21,22,23,24, 640000u,  80} },
        { {25,26,27,28, 1280000u,  1}, {29,30,31,32, 1288000u,  1} },
        { {33,34,35,36, 1296000u,  2}, {37,38,39,40, 1312000u,  2} },
    };
    for (int pi = 0; pi < 3; pi++) {
        const HD& A  = pairs[pi][0];
        const HD& Bx = pairs[pi][1];
        conv3x3_pair_k<<<dim3(16, 16, 2), 256, 0, stream>>>(
            nl[0], nl[1], F(A.w1), F(A.b1), F(Bx.w1), F(Bx.b1), rb0, rb1);
        int gy = (A.co + 15) / 16;
        conv1x1_t<float, float, false><<<dim3(32, gy), 256, 0, stream>>>(
            rb0, F(A.w2), F(A.b2), nullptr, out + A.off, 256, A.co);
        conv1x1_t<float, float, false><<<dim3(32, gy), 256, 0, stream>>>(
            rb1, F(Bx.w2), F(Bx.b2), nullptr, out + Bx.off, 256, Bx.co);
    }
}

// Round 4
// 808.073 us; speedup vs baseline: 11.5999x; 4.6264x over previous
//
#include <hip/hip_runtime.h>
#include <hip/hip_bf16.h>
#include <math.h>
#include <type_traits>

#define NPIX 8000
#define IMH 80
#define IMW 100
#define PW 104
#define PH 82

typedef __attribute__((ext_vector_type(8))) short short8v;
typedef __attribute__((ext_vector_type(4))) short short4v;
typedef __attribute__((ext_vector_type(4))) float f32x4;

__device__ inline short f2bf(float f) {
    __hip_bfloat16 h = __float2bfloat16(f);
    return *reinterpret_cast<short*>(&h);
}
__device__ inline float bf2f(short s) {
    __hip_bfloat16 h;
    *reinterpret_cast<short*>(&h) = s;
    return __bfloat162float(h);
}

// ---------------------------------------------------------------------------
// zero fill (float4 granularity)
// ---------------------------------------------------------------------------
__global__ __launch_bounds__(256) void zero_k(float4* __restrict__ p, int n)
{
    int i = blockIdx.x * 256 + threadIdx.x;
    int stride = gridDim.x * 256;
    float4 z = {0.f, 0.f, 0.f, 0.f};
    for (; i < n; i += stride) p[i] = z;
}

// ---------------------------------------------------------------------------
// Weight transpose: w1 [256co][256ci][9tap] fp32 -> Wt [head][co][tap][ci] bf16
// grid (256 co, 6 heads), 256 threads (thread = ci).
// ---------------------------------------------------------------------------
__global__ __launch_bounds__(256) void wt_transpose_k(
    const float* __restrict__ w0, const float* __restrict__ w1,
    const float* __restrict__ w2, const float* __restrict__ w3,
    const float* __restrict__ w4, const float* __restrict__ w5,
    short* __restrict__ Wt)
{
    const int h = blockIdx.y;
    const float* w = (h == 0) ? w0 : (h == 1) ? w1 : (h == 2) ? w2
                   : (h == 3) ? w3 : (h == 4) ? w4 : w5;
    const int co = blockIdx.x;
    const int ci = threadIdx.x;
    const float* src = w + (size_t)co * 2304 + ci * 9;
    short* dst = Wt + ((size_t)(h * 256 + co) * 9) * 256 + ci;
#pragma unroll
    for (int tap = 0; tap < 9; tap++)
        dst[tap * 256] = f2bf(src[tap]);
}

// ---------------------------------------------------------------------------
// 1x1 conv as GEMM.
// MODE 0: out[co][p] (+res, TO float or short-bf16)
// MODE 1: out[p][Co+co] bf16 (transposed, for phi)
// MODE 2: out[ppx][256] bf16 zero-padded pixel-major (+res), for nl
// ---------------------------------------------------------------------------
template <class TI, class TO, int MODE>
__global__ __launch_bounds__(256) void conv1x1_t(
    const TI* __restrict__ x, const float* __restrict__ w,
    const float* __restrict__ b, const float* __restrict__ res,
    TO* __restrict__ out, int Ci, int Co)
{
    __shared__ __align__(16) float wsT[256 * 20];
    const int tid = threadIdx.x;
    const int co0 = blockIdx.y * 16;

    const int nw = 16 * Ci;
    for (int e = tid; e < nw; e += 256) {
        int co = e / Ci;
        int ci = e - co * Ci;
        float v = 0.f;
        if (co0 + co < Co) v = w[(size_t)(co0 + co) * Ci + ci];
        wsT[ci * 20 + co] = v;
    }
    __syncthreads();

    const int p = blockIdx.x * 256 + tid;
    if (p >= NPIX) return;

    float acc[16];
#pragma unroll
    for (int k = 0; k < 16; k++) acc[k] = 0.f;

#pragma unroll 4
    for (int ci = 0; ci < Ci; ci++) {
        float xv;
        if constexpr (std::is_same_v<TI, short>) {
            short t = x[(size_t)ci * NPIX + p];
            xv = bf2f(t);
        } else {
            xv = x[(size_t)ci * NPIX + p];
        }
        const float4 w0 = *(const float4*)&wsT[ci * 20 + 0];
        const float4 w1 = *(const float4*)&wsT[ci * 20 + 4];
        const float4 w2 = *(const float4*)&wsT[ci * 20 + 8];
        const float4 w3 = *(const float4*)&wsT[ci * 20 + 12];
        acc[0]  += w0.x * xv; acc[1]  += w0.y * xv; acc[2]  += w0.z * xv; acc[3]  += w0.w * xv;
        acc[4]  += w1.x * xv; acc[5]  += w1.y * xv; acc[6]  += w1.z * xv; acc[7]  += w1.w * xv;
        acc[8]  += w2.x * xv; acc[9]  += w2.y * xv; acc[10] += w2.z * xv; acc[11] += w2.w * xv;
        acc[12] += w3.x * xv; acc[13] += w3.y * xv; acc[14] += w3.z * xv; acc[15] += w3.w * xv;
    }

#pragma unroll
    for (int k = 0; k < 16; k++) {
        int co = co0 + k;
        if (co < Co) {
            float v = acc[k] + b[co];
            if constexpr (MODE == 1) {
                out[(size_t)p * Co + co] = (TO)f2bf(v);
            } else if constexpr (MODE == 2) {
                if (res) v += res[(size_t)co * NPIX + p];
                int y = p / 100;
                int xg = p - y * 100;
                size_t ppx = (size_t)(y + 1) * PW + (xg + 1);
                out[ppx * 256 + co] = (TO)f2bf(v);
            } else {
                size_t idx = (size_t)co * NPIX + p;
                if (res) v += res[idx];
                if constexpr (std::is_same_v<TO, short>)
                    out[idx] = f2bf(v);
                else
                    out[idx] = v;
            }
        }
    }
}

// ---------------------------------------------------------------------------
// Transpose raw (8000x128) bf16 view -> [128][8000] bf16. Grid (125,2,2).
// ---------------------------------------------------------------------------
__global__ __launch_bounds__(256) void transp_k(
    const short* __restrict__ g0, short* __restrict__ o0,
    const short* __restrict__ g1, short* __restrict__ o1)
{
    const short* G = blockIdx.z ? g1 : g0;
    short* O = blockIdx.z ? o1 : o0;
    __shared__ __align__(16) short ts[64][68];
    const int tid = threadIdx.x;
    const int q0 = blockIdx.x * 64, d0 = blockIdx.y * 64;

#pragma unroll
    for (int k = 0; k < 4; k++) {
        int f = k * 256 + tid;
        int q = f >> 4, d4 = f & 15;
        *(short4v*)&ts[q][d4 * 4] =
            *(const short4v*)(G + (size_t)(q0 + q) * 128 + d0 + d4 * 4);
    }
    __syncthreads();
#pragma unroll
    for (int k = 0; k < 4; k++) {
        int f = k * 256 + tid;
        int d = f >> 4, q4 = f & 15;
        short4v v;
        v[0] = ts[q4 * 4 + 0][d];
        v[1] = ts[q4 * 4 + 1][d];
        v[2] = ts[q4 * 4 + 2][d];
        v[3] = ts[q4 * 4 + 3][d];
        *(short4v*)(O + (size_t)(d0 + d) * NPIX + q0 + q4 * 4) = v;
    }
}

// ---------------------------------------------------------------------------
// Flash attention with bf16 MFMA (unchanged from round 3, verified).
// ---------------------------------------------------------------------------
__global__ __launch_bounds__(256) void flash_mfma_k(
    const short* __restrict__ th0, const short* __restrict__ pT0,
    const short* __restrict__ gT0, short* __restrict__ y0,
    const short* __restrict__ th1, const short* __restrict__ pT1,
    const short* __restrict__ gT1, short* __restrict__ y1)
{
    const int pb = blockIdx.y;
    const short* TH = pb ? th1 : th0;
    const short* PT = pb ? pT1 : pT0;
    const short* GT = pb ? gT1 : gT0;
    short*       Y  = pb ? y1  : y0;

    __shared__ __align__(16) short kls[64 * 136];
    __shared__ __align__(16) short vls[128 * 72];
    __shared__ __align__(16) short pls[64 * 72];

    const int tid = threadIdx.x;
    const int w = tid >> 6, l = tid & 63, lg = l >> 4, li = l & 15;
    const int r0 = blockIdx.x * 64;
    const int wr = r0 + w * 16;

    short8v qf[4];
#pragma unroll
    for (int ks = 0; ks < 4; ks++)
        qf[ks] = *(const short8v*)(TH + (size_t)(wr + li) * 128 + ks * 32 + lg * 8);

    f32x4 acc_o[8] = {};
    float mj[4] = {-1e30f, -1e30f, -1e30f, -1e30f};
    float lj[4] = {0.f, 0.f, 0.f, 0.f};

    for (int t = 0; t < 125; ++t) {
        const int q0 = t * 64;

#pragma unroll
        for (int k = 0; k < 4; k++) {
            int f = k * 256 + tid;
            int q = f >> 4, c8 = f & 15;
            *(short8v*)(kls + q * 136 + c8 * 8) =
                *(const short8v*)(PT + (size_t)(q0 + q) * 128 + c8 * 8);
        }
#pragma unroll
        for (int k = 0; k < 4; k++) {
            int f = k * 256 + tid;
            int d = f >> 3, q8 = f & 7;
            *(short8v*)(vls + d * 72 + q8 * 8) =
                *(const short8v*)(GT + (size_t)d * NPIX + q0 + q8 * 8);
        }
        __syncthreads();

        f32x4 accs[4] = {};
#pragma unroll
        for (int ks = 0; ks < 4; ks++) {
#pragma unroll
            for (int n = 0; n < 4; n++) {
                short8v bb = *(const short8v*)(kls + (n * 16 + li) * 136 + ks * 32 + lg * 8);
                accs[n] = __builtin_amdgcn_mfma_f32_16x16x32_bf16(qf[ks], bb, accs[n], 0, 0, 0);
            }
        }

#pragma unroll
        for (int j = 0; j < 4; j++) {
            float sm = fmaxf(fmaxf(accs[0][j], accs[1][j]), fmaxf(accs[2][j], accs[3][j]));
            sm = fmaxf(sm, __shfl_xor(sm, 1));
            sm = fmaxf(sm, __shfl_xor(sm, 2));
            sm = fmaxf(sm, __shfl_xor(sm, 4));
            sm = fmaxf(sm, __shfl_xor(sm, 8));
            float mo = mj[j];
            float mn = fmaxf(mo, sm);
            float sc = __expf(mo - mn);
            mj[j] = mn;
            float ps = 0.f;
            int row = w * 16 + lg * 4 + j;
#pragma unroll
            for (int n = 0; n < 4; n++) {
                float pe = __expf(accs[n][j] - mn);
                ps += pe;
                pls[row * 72 + n * 16 + li] = f2bf(pe);
            }
            ps += __shfl_xor(ps, 1);
            ps += __shfl_xor(ps, 2);
            ps += __shfl_xor(ps, 4);
            ps += __shfl_xor(ps, 8);
            lj[j] = lj[j] * sc + ps;
#pragma unroll
            for (int d = 0; d < 8; d++) acc_o[d][j] *= sc;
        }

        __syncthreads();
#pragma unroll
        for (int ks = 0; ks < 2; ks++) {
            short8v aa = *(const short8v*)(pls + (w * 16 + li) * 72 + ks * 32 + lg * 8);
#pragma unroll
            for (int d = 0; d < 8; d++) {
                short8v bb = *(const short8v*)(vls + (d * 16 + li) * 72 + ks * 32 + lg * 8);
                acc_o[d] = __builtin_amdgcn_mfma_f32_16x16x32_bf16(aa, bb, acc_o[d], 0, 0, 0);
            }
        }
        __syncthreads();
    }

#pragma unroll
    for (int d = 0; d < 8; d++) {
#pragma unroll
        for (int j = 0; j < 4; j++) {
            int row = r0 + w * 16 + lg * 4 + j;
            float v = acc_o[d][j] / lj[j];
            Y[(size_t)row * 128 + d * 16 + li] = f2bf(v);
        }
    }
}

// ---------------------------------------------------------------------------
// conv3x3 implicit GEMM via MFMA.
// Input nl_pad [PH*PW][256] bf16, zero-padded. Weights Wt [head][co][tap][ci].
// Block: 256 thr (4 waves). Tile: 64 co x 400 px (8 rows x 50 cols).
// Subtile: 8r x 2c (lane li -> rr=li>>1, cc=li&1); wave w owns n = w,w+4,...
// K-loop: 8 ci-blocks x 9 taps, mfma 16x16x32.
// Output rb[hy][co][8000] bf16 with bias + ReLU.
// grid (80, 3 heads/dispatch).
// ---------------------------------------------------------------------------
#define ASTR 296
#define BSTR 1680

__global__ __launch_bounds__(256) void conv3x3_mfma_k(
    const short* __restrict__ nl0, const short* __restrict__ nl1,
    const short* __restrict__ Wt,
    const float* __restrict__ bias0, const float* __restrict__ bias1,
    const float* __restrict__ bias2,
    short* __restrict__ rb, int hbase)
{
    __shared__ __align__(16) short As[64 * ASTR];
    __shared__ __align__(16) short Bs[10 * BSTR];

    const int tid = threadIdx.x;
    const int hy = blockIdx.y;
    const int h = hbase + hy;
    const short* nlp = (h & 1) ? nl1 : nl0;
    const float* bs = (hy == 0) ? bias0 : (hy == 1) ? bias1 : bias2;
    const short* wth = Wt + (size_t)h * 256 * 9 * 256;
    short* out = rb + (size_t)hy * 256 * NPIX;

    const int bx = blockIdx.x;
    const int co0 = (bx / 20) * 64;
    const int rem = bx % 20;
    const int y0 = (rem >> 1) * 8;
    const int x0 = (rem & 1) * 50;

    const int w = tid >> 6, l = tid & 63, lg = l >> 4, li = l & 15;
    const int rr = li >> 1, cc = li & 1;

    f32x4 acc[4][7] = {};

    const int bbase = (rr + 1) * BSTR + (cc + 1) * 32 + lg * 8;
    const int abase = li * ASTR + lg * 8;

    for (int cb = 0; cb < 8; cb++) {
        __syncthreads();
        // stage B tile: 10 rows x 52 cols x 32 ci
        for (int e = tid; e < 2080; e += 256) {
            int c8 = e & 3;
            int pos = e >> 2;
            int row = pos / 52;
            int col = pos - row * 52;
            *(short8v*)(Bs + row * BSTR + col * 32 + c8 * 8) =
                *(const short8v*)(nlp + ((size_t)(y0 + row) * PW + x0 + col) * 256
                                  + cb * 32 + c8 * 8);
        }
        // stage A tile: 64 co x 9 tap x 32 ci
        for (int e = tid; e < 2304; e += 256) {
            int c8 = e & 3;
            int pos = e >> 2;
            int co = pos / 9;
            int tap = pos - co * 9;
            *(short8v*)(As + co * ASTR + tap * 32 + c8 * 8) =
                *(const short8v*)(wth + ((size_t)(co0 + co) * 9 + tap) * 256
                                  + cb * 32 + c8 * 8);
        }
        __syncthreads();

#pragma unroll
        for (int tap = 0; tap < 9; tap++) {
            const int dy = tap / 3 - 1, dx = tap % 3 - 1;
            short8v af[4];
#pragma unroll
            for (int m = 0; m < 4; m++)
                af[m] = *(const short8v*)(As + abase + m * 16 * ASTR + tap * 32);
            const int boff = bbase + dy * BSTR + dx * 32;
#pragma unroll
            for (int t = 0; t < 7; t++) {
                int n = w + 4 * t;
                if (n < 25) {
                    short8v bf = *(const short8v*)(Bs + boff + n * 64);
#pragma unroll
                    for (int m = 0; m < 4; m++)
                        acc[m][t] = __builtin_amdgcn_mfma_f32_16x16x32_bf16(
                            af[m], bf, acc[m][t], 0, 0, 0);
                }
            }
        }
    }

#pragma unroll
    for (int m = 0; m < 4; m++) {
#pragma unroll
        for (int t = 0; t < 7; t++) {
            int n = w + 4 * t;
            if (n < 25) {
                int xo = x0 + n * 2 + cc;
                int yo = y0 + rr;
#pragma unroll
                for (int j = 0; j < 4; j++) {
                    int co = co0 + m * 16 + lg * 4 + j;
                    float v = acc[m][t][j] + bs[co];
                    out[(size_t)co * NPIX + yo * IMW + xo] = f2bf(fmaxf(v, 0.f));
                }
            }
        }
    }
}

// ---------------------------------------------------------------------------
extern "C" void kernel_launch(void* const* d_in, const int* in_sizes, int n_in,
                              void* d_out, int out_size, void* d_ws, size_t ws_size,
                              hipStream_t stream)
{
    const float* feat = (const float*)d_in[0];
    auto F = [&](int i) { return (const float*)d_in[i]; };

    float* out = (float*)d_out;
    char* base = (char*)d_ws;

    const size_t MB = 1u << 20;
    // QKV bf16 block (dead after flash): 0-16 MB
    short* thb[2] = { (short*)(base + 0 * MB),  (short*)(base + 8 * MB)  };
    short* phT[2] = { (short*)(base + 2 * MB),  (short*)(base + 10 * MB) };
    short* gb[2]  = { (short*)(base + 4 * MB),  (short*)(base + 12 * MB) };
    short* gT[2]  = { (short*)(base + 6 * MB),  (short*)(base + 14 * MB) };
    short* yb[2]  = { (short*)(base + 16 * MB), (short*)(base + 18 * MB) };
    // post-flash regions
    const size_t NLPAD_B = (size_t)PH * PW * 256 * 2;       // 4,366,336 B
    short* nlp0 = (short*)(base + 0);
    short* nlp1 = (short*)(base + NLPAD_B);
    short* rb   = (short*)(base + 10 * MB);                  // 3 x 4,096,000 B
    short* Wt   = (short*)(base + 10 * MB + 3 * (size_t)4096000);

    // 0) weight pre-transpose (region untouched by anything else)
    wt_transpose_k<<<dim3(256, 6), 256, 0, stream>>>(
        F(17), F(21), F(25), F(29), F(33), F(37), Wt);

    // 1) QKV producers
    dim3 gq(32, 8);
    conv1x1_t<float, short, 0><<<gq, 256, 0, stream>>>(feat, F(1),  F(2),  nullptr, thb[0], 256, 128);
    conv1x1_t<float, short, 1><<<gq, 256, 0, stream>>>(feat, F(3),  F(4),  nullptr, phT[0], 256, 128);
    conv1x1_t<float, short, 0><<<gq, 256, 0, stream>>>(feat, F(5),  F(6),  nullptr, gb[0],  256, 128);
    conv1x1_t<float, short, 0><<<gq, 256, 0, stream>>>(feat, F(9),  F(10), nullptr, thb[1], 256, 128);
    conv1x1_t<float, short, 1><<<gq, 256, 0, stream>>>(feat, F(11), F(12), nullptr, phT[1], 256, 128);
    conv1x1_t<float, short, 0><<<gq, 256, 0, stream>>>(feat, F(13), F(14), nullptr, gb[1],  256, 128);

    transp_k<<<dim3(125, 2, 2), 256, 0, stream>>>(gb[0], gT[0], gb[1], gT[1]);

    // 2) attention
    flash_mfma_k<<<dim3(125, 2), 256, 0, stream>>>(thb[0], phT[0], gT[0], yb[0],
                                                   thb[1], phT[1], gT[1], yb[1]);

    // 3) zero padded nl buffers (QKV block now dead), then W-conv + residual
    zero_k<<<1024, 256, 0, stream>>>((float4*)base, (int)(2 * NLPAD_B / 16));
    conv1x1_t<short, short, 2><<<dim3(32, 16), 256, 0, stream>>>(yb[0], F(7),  F(8),  feat, nlp0, 128, 256);
    conv1x1_t<short, short, 2><<<dim3(32, 16), 256, 0, stream>>>(yb[1], F(15), F(16), feat, nlp1, 128, 256);

    // 4) heads, two groups of 3
    struct HD { size_t off; int co; };
    const HD hd[6] = { {0u, 80}, {640000u, 80}, {1280000u, 1},
                       {1288000u, 1}, {1296000u, 2}, {1312000u, 2} };

    for (int grp = 0; grp < 2; grp++) {
        int hb = grp * 3;
        conv3x3_mfma_k<<<dim3(80, 3), 256, 0, stream>>>(
            nlp0, nlp1, Wt, F(18 + 4 * hb), F(18 + 4 * (hb + 1)), F(18 + 4 * (hb + 2)),
            rb, hb);
        for (int k = 0; k < 3; k++) {
            int hh = hb + k;
            int gy = (hd[hh].co + 15) / 16;
            conv1x1_t<short, float, 0><<<dim3(32, gy), 256, 0, stream>>>(
                rb + (size_t)k * 2048000, F(19 + 4 * hh), F(20 + 4 * hh), nullptr,
                out + hd[hh].off, 256, hd[hh].co);
        }
    }
}

// Round 5
// 665.538 us; speedup vs baseline: 14.0842x; 1.2142x over previous
//
#include <hip/hip_runtime.h>
#include <hip/hip_bf16.h>
#include <math.h>
#include <type_traits>

#define NPIX 8000
#define IMH 80
#define IMW 100
#define PW 104
#define PH 82

typedef __attribute__((ext_vector_type(8))) short short8v;
typedef __attribute__((ext_vector_type(4))) short short4v;
typedef __attribute__((ext_vector_type(4))) float f32x4;

__device__ inline short f2bf(float f) {
    __hip_bfloat16 h = __float2bfloat16(f);
    return *reinterpret_cast<short*>(&h);
}
__device__ inline float bf2f(short s) {
    __hip_bfloat16 h;
    *reinterpret_cast<short*>(&h) = s;
    return __bfloat162float(h);
}

// ---------------------------------------------------------------------------
__global__ __launch_bounds__(256) void zero_k(float4* __restrict__ p, int n)
{
    int i = blockIdx.x * 256 + threadIdx.x;
    int stride = gridDim.x * 256;
    float4 z = {0.f, 0.f, 0.f, 0.f};
    for (; i < n; i += stride) p[i] = z;
}

// ---------------------------------------------------------------------------
// feat [256][8000] fp32 -> featT [8000][256] bf16. Grid (125, 4).
// ---------------------------------------------------------------------------
__global__ __launch_bounds__(256) void featT_k(
    const float* __restrict__ feat, short* __restrict__ featT)
{
    __shared__ float ts[64][65];
    const int tid = threadIdx.x;
    const int p0 = blockIdx.x * 64, c0 = blockIdx.y * 64;
#pragma unroll
    for (int it = 0; it < 16; it++) {
        int f = it * 256 + tid;
        int ci = f >> 6, px = f & 63;
        ts[px][ci] = feat[(size_t)(c0 + ci) * NPIX + p0 + px];
    }
    __syncthreads();
#pragma unroll
    for (int it = 0; it < 2; it++) {
        int f = it * 256 + tid;
        int px = f >> 3, c8 = f & 7;
        short8v v;
#pragma unroll
        for (int j = 0; j < 8; j++) v[j] = f2bf(ts[px][c8 * 8 + j]);
        *(short8v*)(featT + (size_t)(p0 + px) * 256 + c0 + c8 * 8) = v;
    }
}

// ---------------------------------------------------------------------------
// 8 weight arrays fp32 -> bf16 (each 32768 elements). Grid (32, 8).
// ---------------------------------------------------------------------------
struct W8 { const float* s[8]; short* d[8]; };
__global__ __launch_bounds__(256) void prep_w8_k(W8 a)
{
    const int z = blockIdx.y;
    const float* s = a.s[z];
    short* d = a.d[z];
    int i = (blockIdx.x * 256 + threadIdx.x) * 4;
    if (i < 32768) {
        float4 v = *(const float4*)(s + i);
        short4v o;
        o[0] = f2bf(v.x); o[1] = f2bf(v.y); o[2] = f2bf(v.z); o[3] = f2bf(v.w);
        *(short4v*)(d + i) = o;
    }
}

// ---------------------------------------------------------------------------
// Weight transpose: [256co][256ci][9tap] fp32 -> Wt [head][co][tap][ci] bf16.
// ---------------------------------------------------------------------------
__global__ __launch_bounds__(256) void wt_transpose_k(
    const float* __restrict__ w0, const float* __restrict__ w1,
    const float* __restrict__ w2, const float* __restrict__ w3,
    const float* __restrict__ w4, const float* __restrict__ w5,
    short* __restrict__ Wt)
{
    const int h = blockIdx.y;
    const float* w = (h == 0) ? w0 : (h == 1) ? w1 : (h == 2) ? w2
                   : (h == 3) ? w3 : (h == 4) ? w4 : w5;
    const int co = blockIdx.x;
    const int ci = threadIdx.x;
    const float* src = w + (size_t)co * 2304 + ci * 9;
    short* dst = Wt + ((size_t)(h * 256 + co) * 9) * 256 + ci;
#pragma unroll
    for (int tap = 0; tap < 9; tap++)
        dst[tap * 256] = f2bf(src[tap]);
}

// ---------------------------------------------------------------------------
// Fused QKV producer GEMM: wqkv [768][256] bf16 x featT [8000][256] bf16.
// Tile 64co x 160px, 4 waves. Row groups: [th0 ph0 g0 th1 ph1 g1] x 128.
// th/g -> channel-major [co'][8000]; ph -> pixel-major [p][128]. Grid (600).
// ---------------------------------------------------------------------------
__global__ __launch_bounds__(256) void qkv_mfma_k(
    const short* __restrict__ featT, const short* __restrict__ wqkv,
    const float* __restrict__ bq0, const float* __restrict__ bq1,
    const float* __restrict__ bq2, const float* __restrict__ bq3,
    const float* __restrict__ bq4, const float* __restrict__ bq5,
    short* __restrict__ th0, short* __restrict__ ph0, short* __restrict__ g0,
    short* __restrict__ th1, short* __restrict__ ph1, short* __restrict__ g1)
{
    __shared__ __align__(16) short As[64 * 40];
    __shared__ __align__(16) short Bs[160 * 40];

    const int tid = threadIdx.x;
    const int bx = blockIdx.x;
    const int co0 = (bx / 50) * 64;
    const int p0 = (bx % 50) * 160;
    const int w = tid >> 6, l = tid & 63, lg = l >> 4, li = l & 15;

    f32x4 acc[4][3] = {};

    for (int cb = 0; cb < 8; cb++) {
        __syncthreads();
        {
            int co = tid >> 2, c8 = tid & 3;
            *(short8v*)(As + co * 40 + c8 * 8) =
                *(const short8v*)(wqkv + (size_t)(co0 + co) * 256 + cb * 32 + c8 * 8);
        }
        for (int e = tid; e < 640; e += 256) {
            int px = e >> 2, c8 = e & 3;
            *(short8v*)(Bs + px * 40 + c8 * 8) =
                *(const short8v*)(featT + (size_t)(p0 + px) * 256 + cb * 32 + c8 * 8);
        }
        __syncthreads();

        short8v af[4];
#pragma unroll
        for (int m = 0; m < 4; m++)
            af[m] = *(const short8v*)(As + (m * 16 + li) * 40 + lg * 8);
#pragma unroll
        for (int t = 0; t < 3; t++) {
            int n = w + 4 * t;
            if (n < 10) {
                short8v bf = *(const short8v*)(Bs + (n * 16 + li) * 40 + lg * 8);
#pragma unroll
                for (int m = 0; m < 4; m++)
                    acc[m][t] = __builtin_amdgcn_mfma_f32_16x16x32_bf16(
                        af[m], bf, acc[m][t], 0, 0, 0);
            }
        }
    }

    const int idx6 = co0 >> 7;
    const int sub = co0 & 127;
    const int kind = idx6 % 3;
    const float* bias = (idx6 == 0) ? bq0 : (idx6 == 1) ? bq1 : (idx6 == 2) ? bq2
                      : (idx6 == 3) ? bq3 : (idx6 == 4) ? bq4 : bq5;
    short* cm = (idx6 == 0) ? th0 : (idx6 == 2) ? g0
              : (idx6 == 3) ? th1 : g1;                 // kind 0 or 2
    short* ph = (idx6 == 1) ? ph0 : ph1;                // kind 1

#pragma unroll
    for (int m = 0; m < 4; m++) {
#pragma unroll
        for (int t = 0; t < 3; t++) {
            int n = w + 4 * t;
            if (n < 10) {
                int p = p0 + n * 16 + li;
#pragma unroll
                for (int j = 0; j < 4; j++) {
                    int co = sub + m * 16 + lg * 4 + j;
                    float v = acc[m][t][j] + bias[co];
                    if (kind == 1)
                        ph[(size_t)p * 128 + co] = f2bf(v);
                    else
                        cm[(size_t)co * NPIX + p] = f2bf(v);
                }
            }
        }
    }
}

// ---------------------------------------------------------------------------
// Transpose raw (8000x128) bf16 view -> [128][8000] bf16. Grid (125,2,2).
// ---------------------------------------------------------------------------
__global__ __launch_bounds__(256) void transp_k(
    const short* __restrict__ g0, short* __restrict__ o0,
    const short* __restrict__ g1, short* __restrict__ o1)
{
    const short* G = blockIdx.z ? g1 : g0;
    short* O = blockIdx.z ? o1 : o0;
    __shared__ __align__(16) short ts[64][68];
    const int tid = threadIdx.x;
    const int q0 = blockIdx.x * 64, d0 = blockIdx.y * 64;

#pragma unroll
    for (int k = 0; k < 4; k++) {
        int f = k * 256 + tid;
        int q = f >> 4, d4 = f & 15;
        *(short4v*)&ts[q][d4 * 4] =
            *(const short4v*)(G + (size_t)(q0 + q) * 128 + d0 + d4 * 4);
    }
    __syncthreads();
#pragma unroll
    for (int k = 0; k < 4; k++) {
        int f = k * 256 + tid;
        int d = f >> 4, q4 = f & 15;
        short4v v;
        v[0] = ts[q4 * 4 + 0][d];
        v[1] = ts[q4 * 4 + 1][d];
        v[2] = ts[q4 * 4 + 2][d];
        v[3] = ts[q4 * 4 + 3][d];
        *(short4v*)(O + (size_t)(d0 + d) * NPIX + q0 + q4 * 4) = v;
    }
}

// ---------------------------------------------------------------------------
// Flash attention, KV-split into 2 halves. Grid (125 qtiles, 2 probs, 2 halves).
// Writes per-half normalized O (bf16) and (m, l) fp32.
// ---------------------------------------------------------------------------
__global__ __launch_bounds__(256) void flash_mfma_k(
    const short* __restrict__ th0, const short* __restrict__ pT0,
    const short* __restrict__ gT0,
    const short* __restrict__ th1, const short* __restrict__ pT1,
    const short* __restrict__ gT1,
    short* __restrict__ ohb, float* __restrict__ mlb)
{
    const int pb = blockIdx.y;
    const int half = blockIdx.z;
    const short* TH = pb ? th1 : th0;
    const short* PT = pb ? pT1 : pT0;
    const short* GT = pb ? gT1 : gT0;
    short* OH = ohb + (size_t)(pb * 2 + half) * 1024000;
    float* ML = mlb + (size_t)(pb * 2 + half) * 16000;

    const int t0 = half ? 63 : 0;
    const int t1 = half ? 125 : 63;

    __shared__ __align__(16) short kls[64 * 136];
    __shared__ __align__(16) short vls[128 * 72];
    __shared__ __align__(16) short pls[64 * 72];

    const int tid = threadIdx.x;
    const int w = tid >> 6, l = tid & 63, lg = l >> 4, li = l & 15;
    const int r0 = blockIdx.x * 64;
    const int wr = r0 + w * 16;

    short8v qf[4];
#pragma unroll
    for (int ks = 0; ks < 4; ks++)
        qf[ks] = *(const short8v*)(TH + (size_t)(wr + li) * 128 + ks * 32 + lg * 8);

    f32x4 acc_o[8] = {};
    float mj[4] = {-1e30f, -1e30f, -1e30f, -1e30f};
    float lj[4] = {0.f, 0.f, 0.f, 0.f};

    for (int t = t0; t < t1; ++t) {
        const int q0 = t * 64;

#pragma unroll
        for (int k = 0; k < 4; k++) {
            int f = k * 256 + tid;
            int q = f >> 4, c8 = f & 15;
            *(short8v*)(kls + q * 136 + c8 * 8) =
                *(const short8v*)(PT + (size_t)(q0 + q) * 128 + c8 * 8);
        }
#pragma unroll
        for (int k = 0; k < 4; k++) {
            int f = k * 256 + tid;
            int d = f >> 3, q8 = f & 7;
            *(short8v*)(vls + d * 72 + q8 * 8) =
                *(const short8v*)(GT + (size_t)d * NPIX + q0 + q8 * 8);
        }
        __syncthreads();

        f32x4 accs[4] = {};
#pragma unroll
        for (int ks = 0; ks < 4; ks++) {
#pragma unroll
            for (int n = 0; n < 4; n++) {
                short8v bb = *(const short8v*)(kls + (n * 16 + li) * 136 + ks * 32 + lg * 8);
                accs[n] = __builtin_amdgcn_mfma_f32_16x16x32_bf16(qf[ks], bb, accs[n], 0, 0, 0);
            }
        }

#pragma unroll
        for (int j = 0; j < 4; j++) {
            float sm = fmaxf(fmaxf(accs[0][j], accs[1][j]), fmaxf(accs[2][j], accs[3][j]));
            sm = fmaxf(sm, __shfl_xor(sm, 1));
            sm = fmaxf(sm, __shfl_xor(sm, 2));
            sm = fmaxf(sm, __shfl_xor(sm, 4));
            sm = fmaxf(sm, __shfl_xor(sm, 8));
            float mo = mj[j];
            float mn = fmaxf(mo, sm);
            float sc = __expf(mo - mn);
            mj[j] = mn;
            float ps = 0.f;
            int row = w * 16 + lg * 4 + j;
#pragma unroll
            for (int n = 0; n < 4; n++) {
                float pe = __expf(accs[n][j] - mn);
                ps += pe;
                pls[row * 72 + n * 16 + li] = f2bf(pe);
            }
            ps += __shfl_xor(ps, 1);
            ps += __shfl_xor(ps, 2);
            ps += __shfl_xor(ps, 4);
            ps += __shfl_xor(ps, 8);
            lj[j] = lj[j] * sc + ps;
#pragma unroll
            for (int d = 0; d < 8; d++) acc_o[d][j] *= sc;
        }

        __syncthreads();
#pragma unroll
        for (int ks = 0; ks < 2; ks++) {
            short8v aa = *(const short8v*)(pls + (w * 16 + li) * 72 + ks * 32 + lg * 8);
#pragma unroll
            for (int d = 0; d < 8; d++) {
                short8v bb = *(const short8v*)(vls + (d * 16 + li) * 72 + ks * 32 + lg * 8);
                acc_o[d] = __builtin_amdgcn_mfma_f32_16x16x32_bf16(aa, bb, acc_o[d], 0, 0, 0);
            }
        }
        __syncthreads();
    }

#pragma unroll
    for (int d = 0; d < 8; d++) {
#pragma unroll
        for (int j = 0; j < 4; j++) {
            int row = r0 + w * 16 + lg * 4 + j;
            float v = acc_o[d][j] / lj[j];
            OH[(size_t)row * 128 + d * 16 + li] = f2bf(v);
        }
    }
    if (li == 0) {
#pragma unroll
        for (int j = 0; j < 4; j++) {
            int row = r0 + w * 16 + lg * 4 + j;
            ML[row] = mj[j];
            ML[8000 + row] = lj[j];
        }
    }
}

// ---------------------------------------------------------------------------
// Combine the two KV halves. Grid (125, 2).
// ---------------------------------------------------------------------------
__global__ __launch_bounds__(256) void combine_k(
    const short* __restrict__ ohb, const float* __restrict__ mlb,
    short* __restrict__ ybb)
{
    const int tid = threadIdx.x;
    const int r0 = blockIdx.x * 64;
    const int prob = blockIdx.y;
    const short* o0 = ohb + (size_t)(prob * 2) * 1024000;
    const short* o1 = o0 + 1024000;
    const float* ml0 = mlb + (size_t)(prob * 2) * 16000;
    const float* ml1 = ml0 + 16000;
    short* yb = ybb + (size_t)prob * 1024000;

#pragma unroll
    for (int it = 0; it < 4; it++) {
        int e = it * 256 + tid;
        int r = r0 + (e >> 4), c8 = e & 15;
        float m0 = ml0[r], l0 = ml0[8000 + r];
        float m1 = ml1[r], l1 = ml1[8000 + r];
        float mm = fmaxf(m0, m1);
        float a0 = l0 * __expf(m0 - mm);
        float a1 = l1 * __expf(m1 - mm);
        float inv = 1.f / (a0 + a1);
        short8v v0 = *(const short8v*)(o0 + (size_t)r * 128 + c8 * 8);
        short8v v1 = *(const short8v*)(o1 + (size_t)r * 128 + c8 * 8);
        short8v o;
#pragma unroll
        for (int j = 0; j < 8; j++)
            o[j] = f2bf((a0 * bf2f(v0[j]) + a1 * bf2f(v1[j])) * inv);
        *(short8v*)(yb + (size_t)r * 128 + c8 * 8) = o;
    }
}

// ---------------------------------------------------------------------------
// W-conv MFMA: nl[p][co] = sum_ci yb[p][ci] Wcv[co][ci] + b[co] + featT[p][co].
// Tile 64px x 64co, K=128, 4 waves (wave = 16 px rows). Grid (125, 4, 2).
// Output zero-padded pixel-major nl_pad [PH*PW][256] bf16.
// ---------------------------------------------------------------------------
__global__ __launch_bounds__(256) void wconv_mfma_k(
    const short* __restrict__ yb0, const short* __restrict__ yb1,
    const short* __restrict__ wcv,
    const float* __restrict__ bw0, const float* __restrict__ bw1,
    const short* __restrict__ featT,
    short* __restrict__ nlp0, short* __restrict__ nlp1)
{
    __shared__ __align__(16) short Ys[64 * 136];
    __shared__ __align__(16) short Ws[64 * 136];

    const int tid = threadIdx.x;
    const int prob = blockIdx.z;
    const short* yb = prob ? yb1 : yb0;
    const short* wc = wcv + (size_t)prob * 32768;
    const float* bw = prob ? bw1 : bw0;
    short* nlp = prob ? nlp1 : nlp0;

    const int p0 = blockIdx.x * 64;
    const int co0 = blockIdx.y * 64;
    const int w = tid >> 6, l = tid & 63, lg = l >> 4, li = l & 15;

#pragma unroll
    for (int it = 0; it < 4; it++) {
        int f = it * 256 + tid;
        int px = f >> 4, c8 = f & 15;
        *(short8v*)(Ys + px * 136 + c8 * 8) =
            *(const short8v*)(yb + (size_t)(p0 + px) * 128 + c8 * 8);
    }
#pragma unroll
    for (int it = 0; it < 4; it++) {
        int f = it * 256 + tid;
        int co = f >> 4, c8 = f & 15;
        *(short8v*)(Ws + co * 136 + c8 * 8) =
            *(const short8v*)(wc + (size_t)(co0 + co) * 128 + c8 * 8);
    }
    __syncthreads();

    f32x4 acc[4] = {};
#pragma unroll
    for (int ks = 0; ks < 4; ks++) {
        short8v af = *(const short8v*)(Ys + (w * 16 + li) * 136 + ks * 32 + lg * 8);
#pragma unroll
        for (int n = 0; n < 4; n++) {
            short8v bf = *(const short8v*)(Ws + (n * 16 + li) * 136 + ks * 32 + lg * 8);
            acc[n] = __builtin_amdgcn_mfma_f32_16x16x32_bf16(af, bf, acc[n], 0, 0, 0);
        }
    }

#pragma unroll
    for (int n = 0; n < 4; n++) {
#pragma unroll
        for (int j = 0; j < 4; j++) {
            int p = p0 + w * 16 + lg * 4 + j;
            int co = co0 + n * 16 + li;
            float v = acc[n][j] + bw[co] + bf2f(featT[(size_t)p * 256 + co]);
            int y = p / 100;
            int x = p - y * 100;
            size_t ppx = (size_t)(y + 1) * PW + (x + 1);
            nlp[ppx * 256 + co] = f2bf(v);
        }
    }
}

// ---------------------------------------------------------------------------
// 1x1 conv (VALU) for heads. out[co][p] fp32.
// ---------------------------------------------------------------------------
__global__ __launch_bounds__(256) void head1x1_k(
    const short* __restrict__ x, const float* __restrict__ w,
    const float* __restrict__ b, float* __restrict__ out, int Co)
{
    __shared__ __align__(16) float wsT[256 * 20];
    const int tid = threadIdx.x;
    const int co0 = blockIdx.y * 16;

    for (int e = tid; e < 16 * 256; e += 256) {
        int co = e >> 8;
        int ci = e & 255;
        float v = 0.f;
        if (co0 + co < Co) v = w[(size_t)(co0 + co) * 256 + ci];
        wsT[ci * 20 + co] = v;
    }
    __syncthreads();

    const int p = blockIdx.x * 256 + tid;
    float acc[16];
#pragma unroll
    for (int k = 0; k < 16; k++) acc[k] = 0.f;

#pragma unroll 4
    for (int ci = 0; ci < 256; ci++) {
        float xv = bf2f(x[(size_t)ci * NPIX + p]);
        const float4 w0 = *(const float4*)&wsT[ci * 20 + 0];
        const float4 w1 = *(const float4*)&wsT[ci * 20 + 4];
        const float4 w2 = *(const float4*)&wsT[ci * 20 + 8];
        const float4 w3 = *(const float4*)&wsT[ci * 20 + 12];
        acc[0]  += w0.x * xv; acc[1]  += w0.y * xv; acc[2]  += w0.z * xv; acc[3]  += w0.w * xv;
        acc[4]  += w1.x * xv; acc[5]  += w1.y * xv; acc[6]  += w1.z * xv; acc[7]  += w1.w * xv;
        acc[8]  += w2.x * xv; acc[9]  += w2.y * xv; acc[10] += w2.z * xv; acc[11] += w2.w * xv;
        acc[12] += w3.x * xv; acc[13] += w3.y * xv; acc[14] += w3.z * xv; acc[15] += w3.w * xv;
    }

#pragma unroll
    for (int k = 0; k < 16; k++) {
        int co = co0 + k;
        if (co < Co)
            out[(size_t)co * NPIX + p] = acc[k] + b[co];
    }
}

// ---------------------------------------------------------------------------
// conv3x3 implicit GEMM via MFMA (round-4 verified), rb via 3 pointers.
// ---------------------------------------------------------------------------
#define ASTR 296
#define BSTR 1680

__global__ __launch_bounds__(256) void conv3x3_mfma_k(
    const short* __restrict__ nl0, const short* __restrict__ nl1,
    const short* __restrict__ Wt,
    const float* __restrict__ bias0, const float* __restrict__ bias1,
    const float* __restrict__ bias2,
    short* __restrict__ rb0, short* __restrict__ rb1, short* __restrict__ rb2,
    int hbase)
{
    __shared__ __align__(16) short As[64 * ASTR];
    __shared__ __align__(16) short Bs[10 * BSTR];

    const int tid = threadIdx.x;
    const int hy = blockIdx.y;
    const int h = hbase + hy;
    const short* nlp = (h & 1) ? nl1 : nl0;
    const float* bs = (hy == 0) ? bias0 : (hy == 1) ? bias1 : bias2;
    const short* wth = Wt + (size_t)h * 256 * 9 * 256;
    short* out = (hy == 0) ? rb0 : (hy == 1) ? rb1 : rb2;

    const int bx = blockIdx.x;
    const int co0 = (bx / 20) * 64;
    const int rem = bx % 20;
    const int y0 = (rem >> 1) * 8;
    const int x0 = (rem & 1) * 50;

    const int w = tid >> 6, l = tid & 63, lg = l >> 4, li = l & 15;
    const int rr = li >> 1, cc = li & 1;

    f32x4 acc[4][7] = {};

    const int bbase = (rr + 1) * BSTR + (cc + 1) * 32 + lg * 8;
    const int abase = li * ASTR + lg * 8;

    for (int cb = 0; cb < 8; cb++) {
        __syncthreads();
        for (int e = tid; e < 2080; e += 256) {
            int c8 = e & 3;
            int pos = e >> 2;
            int row = pos / 52;
            int col = pos - row * 52;
            *(short8v*)(Bs + row * BSTR + col * 32 + c8 * 8) =
                *(const short8v*)(nlp + ((size_t)(y0 + row) * PW + x0 + col) * 256
                                  + cb * 32 + c8 * 8);
        }
        for (int e = tid; e < 2304; e += 256) {
            int c8 = e & 3;
            int pos = e >> 2;
            int co = pos / 9;
            int tap = pos - co * 9;
            *(short8v*)(As + co * ASTR + tap * 32 + c8 * 8) =
                *(const short8v*)(wth + ((size_t)(co0 + co) * 9 + tap) * 256
                                  + cb * 32 + c8 * 8);
        }
        __syncthreads();

#pragma unroll
        for (int tap = 0; tap < 9; tap++) {
            const int dy = tap / 3 - 1, dx = tap % 3 - 1;
            short8v af[4];
#pragma unroll
            for (int m = 0; m < 4; m++)
                af[m] = *(const short8v*)(As + abase + m * 16 * ASTR + tap * 32);
            const int boff = bbase + dy * BSTR + dx * 32;
#pragma unroll
            for (int t = 0; t < 7; t++) {
                int n = w + 4 * t;
                if (n < 25) {
                    short8v bf = *(const short8v*)(Bs + boff + n * 64);
#pragma unroll
                    for (int m = 0; m < 4; m++)
                        acc[m][t] = __builtin_amdgcn_mfma_f32_16x16x32_bf16(
                            af[m], bf, acc[m][t], 0, 0, 0);
                }
            }
        }
    }

#pragma unroll
    for (int m = 0; m < 4; m++) {
#pragma unroll
        for (int t = 0; t < 7; t++) {
            int n = w + 4 * t;
            if (n < 25) {
                int xo = x0 + n * 2 + cc;
                int yo = y0 + rr;
#pragma unroll
                for (int j = 0; j < 4; j++) {
                    int co = co0 + m * 16 + lg * 4 + j;
                    float v = acc[m][t][j] + bs[co];
                    out[(size_t)co * NPIX + yo * IMW + xo] = f2bf(fmaxf(v, 0.f));
                }
            }
        }
    }
}

// ---------------------------------------------------------------------------
extern "C" void kernel_launch(void* const* d_in, const int* in_sizes, int n_in,
                              void* d_out, int out_size, void* d_ws, size_t ws_size,
                              hipStream_t stream)
{
    const float* feat = (const float*)d_in[0];
    auto F = [&](int i) { return (const float*)d_in[i]; };

    float* out = (float*)d_out;
    char* base = (char*)d_ws;

    // -------- workspace layout (bytes) --------
    short* featT  = (short*)(base);                       // 4,096,000
    short* wcv    = (short*)(base + 4096000);             //   131,072
    short* wqkv   = (short*)(base + 4227072);             //   393,216
    char*  Bb     = base + 4620288;                       // 12,288,000
    short* thb[2] = {(short*)(Bb + 0),        (short*)(Bb + 6144000)};
    short* phT[2] = {(short*)(Bb + 2048000),  (short*)(Bb + 8192000)};
    short* gb[2]  = {(short*)(Bb + 4096000),  (short*)(Bb + 10240000)};
    short* gT[2]  = {(short*)(base + 16908288), (short*)(base + 18956288)};
    short* ohb    = (short*)(base + 21004288);            // 8,192,000
    float* mlb    = (float*)(base + 29196288);            //   256,000
    // post-flash reuse
    short* yb[2]  = {(short*)(base + 4620288), (short*)(base + 6668288)};
    short* Wt     = (short*)(base + 8716288);             // 7,077,888
    short* nlp0   = (short*)(base + 16908288);            // 4,366,336
    short* nlp1   = (short*)(base + 21274624);            // 4,366,336
    short* rb[3]  = {(short*)(base + 0), (short*)(base + 4096000),
                     (short*)(base + 25640960)};

    // 1) feat -> featT bf16 pixel-major
    featT_k<<<dim3(125, 4), 256, 0, stream>>>(feat, featT);

    // 2) weight prep (qkv 6x + wconv 2x)
    W8 wa;
    wa.s[0] = F(1);  wa.s[1] = F(3);  wa.s[2] = F(5);
    wa.s[3] = F(9);  wa.s[4] = F(11); wa.s[5] = F(13);
    wa.s[6] = F(7);  wa.s[7] = F(15);
    for (int z = 0; z < 6; z++) wa.d[z] = wqkv + (size_t)z * 32768;
    wa.d[6] = wcv; wa.d[7] = wcv + 32768;
    prep_w8_k<<<dim3(32, 8), 256, 0, stream>>>(wa);

    // 3) fused QKV GEMM
    qkv_mfma_k<<<dim3(600), 256, 0, stream>>>(
        featT, wqkv, F(2), F(4), F(6), F(10), F(12), F(14),
        thb[0], phT[0], gb[0], thb[1], phT[1], gb[1]);

    // 4) g transpose
    transp_k<<<dim3(125, 2, 2), 256, 0, stream>>>(gb[0], gT[0], gb[1], gT[1]);

    // 5) flash attention, KV-split 2
    flash_mfma_k<<<dim3(125, 2, 2), 256, 0, stream>>>(
        thb[0], phT[0], gT[0], thb[1], phT[1], gT[1], ohb, mlb);

    // 6) combine halves -> yb
    combine_k<<<dim3(125, 2), 256, 0, stream>>>(ohb, mlb, (short*)(base + 4620288));

    // 7) conv3x3 weight transpose (into dead QKV region)
    wt_transpose_k<<<dim3(256, 6), 256, 0, stream>>>(
        F(17), F(21), F(25), F(29), F(33), F(37), Wt);

    // 8) zero nl pads, then W-conv (+bias +residual) -> nl_pad pixel-major
    zero_k<<<1024, 256, 0, stream>>>((float4*)(base + 16908288), 545792);
    wconv_mfma_k<<<dim3(125, 4, 2), 256, 0, stream>>>(
        yb[0], yb[1], wcv, F(8), F(16), featT, nlp0, nlp1);

    // 9) heads: 2 groups of 3 (conv3x3 MFMA + 1x1)
    struct HD { size_t off; int co; };
    const HD hd[6] = { {0u, 80}, {640000u, 80}, {1280000u, 1},
                       {1288000u, 1}, {1296000u, 2}, {1312000u, 2} };

    for (int grp = 0; grp < 2; grp++) {
        int hb = grp * 3;
        conv3x3_mfma_k<<<dim3(80, 3), 256, 0, stream>>>(
            nlp0, nlp1, Wt, F(18 + 4 * hb), F(18 + 4 * (hb + 1)), F(18 + 4 * (hb + 2)),
            rb[0], rb[1], rb[2], hb);
        for (int k = 0; k < 3; k++) {
            int hh = hb + k;
            int gy = (hd[hh].co + 15) / 16;
            head1x1_k<<<dim3(32, gy), 256, 0, stream>>>(
                rb[k], F(19 + 4 * hh), F(20 + 4 * hh), out + hd[hh].off, hd[hh].co);
        }
    }
}